// Round 2
// baseline (441.892 us; speedup 1.0000x reference)
//
#include <hip/hip_runtime.h>
#include <math.h>

// CRF negative log-likelihood, fused single kernel. Round 2.
// B=16384, M=16, D=128, L=26.
// One wave64 per batch element. lane = 2*k2 + h:
//   - W[k2][h*64..h*64+63] in registers (64 VGPRs)
//   - emissions: broadcast float4 global loads of X (no LDS staging; L1 serves)
//   - recurrence: alpha via ds_bpermute from even lanes; T columns in regs
// LDS: Ts (node/edge lookup) + Es (node potential gather) + block-reduce pad.

#define B_TOT 16384
#define M_LEN 16
#define D_DIM 128
#define L_LAB 26
#define WPB 4
#define NBLOCKS (B_TOT / WPB)   // 4096 blocks, 1 batch per wave

__global__ __launch_bounds__(256, 4) void crf_kernel(
    const float* __restrict__ X, const int* __restrict__ Y,
    const float* __restrict__ W, const float* __restrict__ T,
    float* __restrict__ out)
{
    const int lane = threadIdx.x & 63;
    const int wave = threadIdx.x >> 6;
    const int k2 = lane >> 1;            // label slot 0..31 (valid < 26)
    const int h  = lane & 1;             // feature-half / k-half selector
    const int jj = (k2 < L_LAB) ? k2 : 0;

    __shared__ float Ts[L_LAB * L_LAB];          // 2.7 KB
    __shared__ float Es[WPB][M_LEN * L_LAB];     // 6.5 KB
    __shared__ float red[WPB];

    for (int i = threadIdx.x; i < L_LAB * L_LAB; i += 256) Ts[i] = T[i];

    // W fragment in registers: lane (k2,h) holds W[k2][h*64 + 0..63]
    float4 Wr[16];
    if (k2 < L_LAB) {
        const float4* wp = (const float4*)(W + k2 * D_DIM + h * 64);
        #pragma unroll
        for (int i = 0; i < 16; ++i) Wr[i] = wp[i];
    } else {
        #pragma unroll
        for (int i = 0; i < 16; ++i) Wr[i] = make_float4(0.f, 0.f, 0.f, 0.f);
    }

    // T columns in registers: Tr[u] = T[h*13+u][jj]
    float Tr[13];
    #pragma unroll
    for (int u = 0; u < 13; ++u) Tr[u] = T[(h * 13 + u) * L_LAB + jj];

    __syncthreads();  // Ts ready (only block-shared data)

    const int b = blockIdx.x * WPB + wave;
    const float* xb = X + (size_t)b * (M_LEN * D_DIM);

    // ---- emissions: emit[s][k2] = <X[b][s], W[k2]>, straight from global ----
    for (int s = 0; s < M_LEN; ++s) {
        const float4* xr = (const float4*)(xb + s * D_DIM + h * 64);
        float a0 = 0.f, a1 = 0.f, a2 = 0.f, a3 = 0.f;
        #pragma unroll
        for (int i = 0; i < 4; ++i) {
            float4 x0 = xr[4 * i + 0], x1 = xr[4 * i + 1];
            float4 x2 = xr[4 * i + 2], x3 = xr[4 * i + 3];
            a0 += x0.x * Wr[4*i+0].x + x0.y * Wr[4*i+0].y + x0.z * Wr[4*i+0].z + x0.w * Wr[4*i+0].w;
            a1 += x1.x * Wr[4*i+1].x + x1.y * Wr[4*i+1].y + x1.z * Wr[4*i+1].z + x1.w * Wr[4*i+1].w;
            a2 += x2.x * Wr[4*i+2].x + x2.y * Wr[4*i+2].y + x2.z * Wr[4*i+2].z + x2.w * Wr[4*i+2].w;
            a3 += x3.x * Wr[4*i+3].x + x3.y * Wr[4*i+3].y + x3.z * Wr[4*i+3].z + x3.w * Wr[4*i+3].w;
        }
        float acc = (a0 + a1) + (a2 + a3);
        acc += __shfl_xor(acc, 1);               // combine the two d-halves
        if (h == 0 && k2 < L_LAB) Es[wave][s * L_LAB + k2] = acc;
    }
    // Es written and read by the same wave only: DS ops are in-order, no barrier.

    // ---- node + edge potentials ----
    float ne = 0.f;
    if (lane < M_LEN) {
        int ys = Y[(size_t)b * M_LEN + lane];
        ne = Es[wave][lane * L_LAB + ys];
        if (lane < M_LEN - 1) {
            int yn = Y[(size_t)b * M_LEN + lane + 1];
            ne += Ts[ys * L_LAB + yn];
        }
    }
    #pragma unroll
    for (int off = 32; off >= 1; off >>= 1) ne += __shfl_xor(ne, off);

    // ---- forward recurrence (15 steps) ----
    // even lane 2k holds ae for label k; bpermute base addr is a per-lane const
    float alpha = 0.f;
    const int baddr = 104 * h;   // byte index of lane 2*(13h): 4 * 2 * 13h
    for (int s = 0; s < M_LEN - 1; ++s) {
        float ae = alpha + Es[wave][s * L_LAB + jj];
        int aei = __float_as_int(ae);
        float t[13];
        #pragma unroll
        for (int u = 0; u < 13; ++u) {
            t[u] = __int_as_float(__builtin_amdgcn_ds_bpermute(baddr + 8 * u, aei)) + Tr[u];
        }
        float m0 = fmaxf(fmaxf(fmaxf(t[0], t[1]), fmaxf(t[2], t[3])),
                         fmaxf(fmaxf(t[4], t[5]), fmaxf(t[6], t[7])));
        float m1 = fmaxf(fmaxf(fmaxf(t[8], t[9]), fmaxf(t[10], t[11])), t[12]);
        float m = fmaxf(m0, m1);
        m = fmaxf(m, __shfl_xor(m, 1));          // max over all 26 k
        float s0 = 0.f, s1 = 0.f;
        #pragma unroll
        for (int u = 0; u < 12; u += 2) {
            s0 += __expf(t[u] - m);
            s1 += __expf(t[u + 1] - m);
        }
        s0 += __expf(t[12] - m);
        float ss = s0 + s1;
        ss += __shfl_xor(ss, 1);                 // sum over all 26 k
        alpha = m + __logf(ss);
    }

    // ---- log partition ----
    float fin = (h == 0 && k2 < L_LAB) ? (alpha + Es[wave][(M_LEN - 1) * L_LAB + k2]) : -1e30f;
    float mz = fin;
    #pragma unroll
    for (int off = 32; off >= 1; off >>= 1) mz = fmaxf(mz, __shfl_xor(mz, off));
    float ez = (h == 0 && k2 < L_LAB) ? __expf(fin - mz) : 0.f;
    #pragma unroll
    for (int off = 32; off >= 1; off >>= 1) ez += __shfl_xor(ez, off);
    float logz = mz + __logf(ez);

    float local = logz - ne;

    if (lane == 0) red[wave] = local;
    __syncthreads();
    if (threadIdx.x == 0) {
        atomicAdd(out, (red[0] + red[1]) + (red[2] + red[3]));
    }
}

extern "C" void kernel_launch(void* const* d_in, const int* in_sizes, int n_in,
                              void* d_out, int out_size, void* d_ws, size_t ws_size,
                              hipStream_t stream) {
    const float* X = (const float*)d_in[0];
    const int*   Y = (const int*)d_in[1];
    const float* W = (const float*)d_in[2];
    const float* T = (const float*)d_in[3];
    float* out = (float*)d_out;

    hipMemsetAsync(out, 0, sizeof(float), stream);
    crf_kernel<<<NBLOCKS, 256, 0, stream>>>(X, Y, W, T, out);
}

// Round 3
// 232.023 us; speedup vs baseline: 1.9045x; 1.9045x over previous
//
#include <hip/hip_runtime.h>
#include <math.h>

// CRF negative log-likelihood. Round 3: MFMA emissions + log2-domain recurrence.
// B=16384, M=16, D=128, L=26. One wave64 per batch element.
//
// Emissions: emit2[s][k] = <X[b][s], W[k]*log2e> via v_mfma_f32_16x16x32_bf16,
//   2 label-tiles (0-15, 16-31 zero-padded) x 4 K-steps (K=128).
//   W fragments precomputed into d_ws by prep_kernel (bf16, pre-scaled, padded).
// Recurrence in bits (log2): alpha2[j] = log2 sum_k 2^{alpha2[k]+e2[k]+T2[k][j]},
//   stabilized by subtracting lane-0 alpha (offset accumulated in scalar).
// node potential = sum Es*ln2; edge from natural-units Ts in LDS.

#define B_TOT 16384
#define M_LEN 16
#define D_DIM 128
#define L_LAB 26
#define WPB 4
#define NBLOCKS (B_TOT / WPB)
#define LOG2E 1.4426950408889634f
#define LN2   0.6931471805599453f

typedef short v8s __attribute__((ext_vector_type(8)));   // 8 bf16 (4 VGPRs)
typedef float v4f __attribute__((ext_vector_type(4)));   // 4 fp32 acc

static __device__ __forceinline__ unsigned bf16u(float f) {
    unsigned u = __float_as_uint(f);
    u += 0x7fff + ((u >> 16) & 1);     // round-to-nearest-even
    return u >> 16;
}
static __device__ __forceinline__ unsigned pkbf(float lo, float hi) {
    return bf16u(lo) | (bf16u(hi) << 16);
}
static __device__ __forceinline__ float fexp2(float x) {
#if __has_builtin(__builtin_amdgcn_exp2f)
    return __builtin_amdgcn_exp2f(x);
#else
    return exp2f(x);
#endif
}
static __device__ __forceinline__ float flog2(float x) {
#if __has_builtin(__builtin_amdgcn_logf)
    return __builtin_amdgcn_logf(x);
#else
    return log2f(x);
#endif
}

// Precompute B-operand MFMA fragments of W*log2e (bf16, labels padded to 32).
// Fragment f = tile*4 + kstep; lane l holds W2[tile*16 + (l&15)][kstep*32 + (l>>4)*8 + j], j=0..7.
// Layout in ws: uint4 wsW[64][8] (lane-major, 128 B per lane).
__global__ void prep_kernel(const float* __restrict__ W, uint4* __restrict__ wsW) {
    const int l = threadIdx.x;       // 0..63
    const int c16 = l & 15, quad = l >> 4;
    #pragma unroll
    for (int f = 0; f < 8; ++f) {
        const int tile = f >> 2, kk = f & 3;
        const int label = tile * 16 + c16;
        const int base = kk * 32 + quad * 8;
        unsigned d[4];
        #pragma unroll
        for (int p = 0; p < 4; ++p) {
            float a = 0.f, bb = 0.f;
            if (label < L_LAB) {
                a  = W[label * D_DIM + base + 2 * p]     * LOG2E;
                bb = W[label * D_DIM + base + 2 * p + 1] * LOG2E;
            }
            d[p] = pkbf(a, bb);
        }
        wsW[l * 8 + f] = make_uint4(d[0], d[1], d[2], d[3]);
    }
}

__global__ __launch_bounds__(256, 4) void crf_kernel(
    const float* __restrict__ X, const int* __restrict__ Y,
    const float* __restrict__ T, const uint4* __restrict__ wsW,
    float* __restrict__ out)
{
    const int lane = threadIdx.x & 63;
    const int wave = threadIdx.x >> 6;
    const int k2 = lane >> 1;                 // label slot (recurrence), valid < 26
    const int h  = lane & 1;
    const int jj = (k2 < L_LAB) ? k2 : 0;
    const int c16 = lane & 15;                // MFMA col/row-group
    const int quad = lane >> 4;

    __shared__ float Ts[L_LAB * L_LAB];       // natural units, for edge potential
    __shared__ float Es[WPB][M_LEN * 32];     // emissions in bits (e*log2e), padded stride 32
    __shared__ float red[WPB];

    for (int i = threadIdx.x; i < L_LAB * L_LAB; i += 256) Ts[i] = T[i];

    // W fragments (ready-made bf16, pre-scaled): 8 x dwordx4 per lane
    uint4 wf[8];
    #pragma unroll
    for (int f = 0; f < 8; ++f) wf[f] = wsW[lane * 8 + f];

    // T columns in bits: Tr2[u] = T[h*13+u][jj] * log2e
    float Tr2[13];
    #pragma unroll
    for (int u = 0; u < 13; ++u) Tr2[u] = T[(h * 13 + u) * L_LAB + jj] * LOG2E;

    __syncthreads();   // Ts ready

    const int b = blockIdx.x * WPB + wave;
    const float* xb = X + (size_t)b * (M_LEN * D_DIM);

    // ---- emissions via MFMA: acc[tile] = X_bf16 . W2_frag ----
    v4f acc0 = {0.f, 0.f, 0.f, 0.f};
    v4f acc1 = {0.f, 0.f, 0.f, 0.f};
    #pragma unroll
    for (int kk = 0; kk < 4; ++kk) {
        const float4* xp = (const float4*)(xb + c16 * D_DIM + kk * 32 + quad * 8);
        float4 xa = xp[0];
        float4 xc = xp[1];
        uint4 au = make_uint4(pkbf(xa.x, xa.y), pkbf(xa.z, xa.w),
                              pkbf(xc.x, xc.y), pkbf(xc.z, xc.w));
        v8s af = *(v8s*)&au;
        v8s b0 = *(v8s*)&wf[kk];
        v8s b1 = *(v8s*)&wf[4 + kk];
        acc0 = __builtin_amdgcn_mfma_f32_16x16x32_bf16(af, b0, acc0, 0, 0, 0);
        acc1 = __builtin_amdgcn_mfma_f32_16x16x32_bf16(af, b1, acc1, 0, 0, 0);
    }
    // C layout: col = lane&15, row s = quad*4 + reg
    #pragma unroll
    for (int r = 0; r < 4; ++r) {
        const int s = quad * 4 + r;
        Es[wave][s * 32 + c16] = acc0[r];
        Es[wave][s * 32 + 16 + c16] = acc1[r];   // labels 26..31 land in pad, never read
    }
    // Es written & read by the same wave only: DS ops in-order, no barrier needed.

    // ---- node + edge potentials ----
    float ne = 0.f;
    if (lane < M_LEN) {
        const int ys = Y[(size_t)b * M_LEN + lane];
        ne = Es[wave][lane * 32 + ys] * LN2;          // bits -> nats
        if (lane < M_LEN - 1) {
            const int yn = Y[(size_t)b * M_LEN + lane + 1];
            ne += Ts[ys * L_LAB + yn];
        }
    }
    #pragma unroll
    for (int off = 32; off >= 1; off >>= 1) ne += __shfl_xor(ne, off);

    // ---- forward recurrence (15 steps), log2 domain, offset-stabilized ----
    float alpha = 0.f, offs = 0.f;
    const int baddr = 104 * h;    // byte addr of lane 2*(13h)
    for (int s = 0; s < M_LEN - 1; ++s) {
        const float c = __shfl(alpha, 0);
        const float ae = alpha - c + Es[wave][s * 32 + jj];
        const int aei = __float_as_int(ae);
        float s0 = 0.f, s1 = 0.f;
        #pragma unroll
        for (int u = 0; u < 12; u += 2) {
            float t0 = __int_as_float(__builtin_amdgcn_ds_bpermute(baddr + 8 * u, aei)) + Tr2[u];
            float t1 = __int_as_float(__builtin_amdgcn_ds_bpermute(baddr + 8 * u + 8, aei)) + Tr2[u + 1];
            s0 += fexp2(t0);
            s1 += fexp2(t1);
        }
        s0 += fexp2(__int_as_float(__builtin_amdgcn_ds_bpermute(baddr + 96, aei)) + Tr2[12]);
        float ss = s0 + s1;
        ss += __shfl_xor(ss, 1);
        alpha = flog2(ss);
        offs += c;
    }

    // ---- log partition (bits -> nats) ----
    const float fin = (h == 0 && k2 < L_LAB) ? (alpha + Es[wave][(M_LEN - 1) * 32 + k2]) : 0.f;
    float ez = (h == 0 && k2 < L_LAB) ? fexp2(fin) : 0.f;
    #pragma unroll
    for (int off = 32; off >= 1; off >>= 1) ez += __shfl_xor(ez, off);
    const float logz = (flog2(ez) + offs) * LN2;

    const float local = logz - ne;
    if (lane == 0) red[wave] = local;
    __syncthreads();
    if (threadIdx.x == 0) atomicAdd(out, (red[0] + red[1]) + (red[2] + red[3]));
}

extern "C" void kernel_launch(void* const* d_in, const int* in_sizes, int n_in,
                              void* d_out, int out_size, void* d_ws, size_t ws_size,
                              hipStream_t stream) {
    const float* X = (const float*)d_in[0];
    const int*   Y = (const int*)d_in[1];
    const float* W = (const float*)d_in[2];
    const float* T = (const float*)d_in[3];
    float* out = (float*)d_out;
    uint4* wsW = (uint4*)d_ws;   // 64 lanes x 8 frags x 16 B = 8 KB

    hipMemsetAsync(out, 0, sizeof(float), stream);
    prep_kernel<<<1, 64, 0, stream>>>(W, wsW);
    crf_kernel<<<NBLOCKS, 256, 0, stream>>>(X, Y, T, wsW, out);
}

// Round 4
// 215.769 us; speedup vs baseline: 2.0480x; 1.0753x over previous
//
#include <hip/hip_runtime.h>
#include <math.h>

// CRF negative log-likelihood. Round 4: transcendental-free recurrence.
// B=16384, M=16, D=128, L=26. 2 batches per wave (lane = 32g + j).
//
// v_s[j] = 2^{alpha_s[j] + e2[s][j] - s*delta};  v_0 = E_0;
// v_s = (v_{s-1} . P') * E_s,  P'[k][j] = 2^{T2[k][j] - delta} (constant),
// E_s[j] = 2^{e2[s][j]} (from MFMA emissions, exponentiated once).
// logZ = (log2(sum_k v_15[k]) + 15*delta) * ln2.  No exp/log in the loop.

#define B_TOT 16384
#define M_LEN 16
#define D_DIM 128
#define L_LAB 26
#define WPB 4
#define NBLOCKS (B_TOT / (WPB * 2))   // 2048 blocks, 2 batches per wave
#define LOG2E 1.4426950408889634f
#define LN2   0.6931471805599453f
#define DELTA 5.7f
#define ESTR 36                        // E row stride in floats (16B-aligned, conflict-safe)

typedef short v8s __attribute__((ext_vector_type(8)));   // 8 bf16
typedef float v4f __attribute__((ext_vector_type(4)));   // 4 fp32 acc

static __device__ __forceinline__ unsigned bf16u(float f) {
    unsigned u = __float_as_uint(f);
    u += 0x7fff + ((u >> 16) & 1);     // RNE
    return u >> 16;
}
static __device__ __forceinline__ unsigned pkbf(float lo, float hi) {
    return bf16u(lo) | (bf16u(hi) << 16);
}
static __device__ __forceinline__ float fexp2(float x) {
#if __has_builtin(__builtin_amdgcn_exp2f)
    return __builtin_amdgcn_exp2f(x);
#else
    return exp2f(x);
#endif
}
static __device__ __forceinline__ float flog2(float x) {
#if __has_builtin(__builtin_amdgcn_logf)
    return __builtin_amdgcn_logf(x);
#else
    return log2f(x);
#endif
}

// Precompute (a) W MFMA B-fragments, bf16, scaled by log2e, labels zero-padded
// to 32; (b) P' transposed: wsP[j*32+k] = 2^{T[k][j]*log2e - delta}, zero pad.
__global__ void prep_kernel(const float* __restrict__ W, const float* __restrict__ T,
                            uint4* __restrict__ wsW, float* __restrict__ wsP) {
    const int l = threadIdx.x;       // 64 threads
    const int c16 = l & 15, quad = l >> 4;
    #pragma unroll
    for (int f = 0; f < 8; ++f) {
        const int tile = f >> 2, kk = f & 3;
        const int label = tile * 16 + c16;
        const int base = kk * 32 + quad * 8;
        unsigned d[4];
        #pragma unroll
        for (int p = 0; p < 4; ++p) {
            float a = 0.f, bb = 0.f;
            if (label < L_LAB) {
                a  = W[label * D_DIM + base + 2 * p]     * LOG2E;
                bb = W[label * D_DIM + base + 2 * p + 1] * LOG2E;
            }
            d[p] = pkbf(a, bb);
        }
        wsW[l * 8 + f] = make_uint4(d[0], d[1], d[2], d[3]);
    }
    for (int i = l; i < 1024; i += 64) {
        const int j = i >> 5, k = i & 31;
        wsP[i] = (j < L_LAB && k < L_LAB)
               ? exp2f(T[k * L_LAB + j] * LOG2E - DELTA) : 0.f;
    }
}

__global__ __launch_bounds__(256, 4) void crf_kernel(
    const float* __restrict__ X, const int* __restrict__ Y,
    const float* __restrict__ T, const uint4* __restrict__ wsW,
    const float* __restrict__ wsP, float* __restrict__ out)
{
    const int lane = threadIdx.x & 63;
    const int wave = threadIdx.x >> 6;
    const int g = lane >> 5;             // batch half
    const int j = lane & 31;             // label (valid < 26)
    const int c16 = lane & 15;           // MFMA col / row-group
    const int quad = lane >> 4;

    __shared__ float Ts[L_LAB * L_LAB];                // natural units (edge)
    __shared__ float Ee[WPB][2][M_LEN * ESTR];         // E = 2^{e2}, 18.4 KB
    __shared__ float vrow[WPB][2][ESTR];
    __shared__ float red[WPB];

    for (int i = threadIdx.x; i < L_LAB * L_LAB; i += 256) Ts[i] = T[i];

    // W fragments (bf16, pre-scaled) and P' column for this lane's j
    uint4 wf[8];
    #pragma unroll
    for (int f = 0; f < 8; ++f) wf[f] = wsW[lane * 8 + f];
    float Pc[26];
    {
        const float* pp = wsP + j * 32;
        #pragma unroll
        for (int k = 0; k < 26; ++k) Pc[k] = pp[k];
    }

    __syncthreads();   // Ts ready

    const int wgid = blockIdx.x * WPB + wave;

    // ---- emissions via MFMA, 2 batches, epilogue applies exp2 ----
    #pragma unroll
    for (int g2 = 0; g2 < 2; ++g2) {
        const float* xb = X + (size_t)(wgid * 2 + g2) * (M_LEN * D_DIM);
        v4f acc0 = {0.f, 0.f, 0.f, 0.f};
        v4f acc1 = {0.f, 0.f, 0.f, 0.f};
        #pragma unroll
        for (int kk = 0; kk < 4; ++kk) {
            const float4* xp = (const float4*)(xb + c16 * D_DIM + kk * 32 + quad * 8);
            float4 xa = xp[0];
            float4 xc = xp[1];
            uint4 au = make_uint4(pkbf(xa.x, xa.y), pkbf(xa.z, xa.w),
                                  pkbf(xc.x, xc.y), pkbf(xc.z, xc.w));
            v8s af = *(v8s*)&au;
            v8s b0 = *(v8s*)&wf[kk];
            v8s b1 = *(v8s*)&wf[4 + kk];
            acc0 = __builtin_amdgcn_mfma_f32_16x16x32_bf16(af, b0, acc0, 0, 0, 0);
            acc1 = __builtin_amdgcn_mfma_f32_16x16x32_bf16(af, b1, acc1, 0, 0, 0);
        }
        // C layout: col = lane&15 (label), row s = quad*4 + r (position)
        #pragma unroll
        for (int r = 0; r < 4; ++r) {
            const int s = quad * 4 + r;
            Ee[wave][g2][s * ESTR + c16]      = fexp2(acc0[r]);
            Ee[wave][g2][s * ESTR + 16 + c16] = fexp2(acc1[r]);  // labels>=26: e2=0 -> E=1
        }
    }
    // Ee written & read by the same wave only: DS pipe is in-order, no barrier.

    // ---- node + edge potentials (e2 recovered via log2(E)) ----
    float ne = 0.f;
    if (j < M_LEN) {                       // lanes 0-15 (g=0) and 32-47 (g=1)
        const int bb = wgid * 2 + g;
        const int ys = Y[bb * M_LEN + j];
        ne = flog2(Ee[wave][g][j * ESTR + ys]) * LN2;
        if (j < M_LEN - 1) {
            const int yn = Y[bb * M_LEN + j + 1];
            ne += Ts[ys * L_LAB + yn];
        }
    }
    ne += __shfl_xor(ne, 8);
    ne += __shfl_xor(ne, 4);
    ne += __shfl_xor(ne, 2);
    ne += __shfl_xor(ne, 1);               // valid in lanes with (lane&31)<16, incl. 32g

    // ---- recurrence: 15 x (fp32 matvec + elementwise E), no transcendentals ----
    float v[26];
    {
        const float* er = &Ee[wave][g][0];           // broadcast per half
        #pragma unroll
        for (int k = 0; k < 26; ++k) v[k] = er[k];   // v_0 = E_0
    }
    for (int s = 1; s < M_LEN; ++s) {
        const float Ej = Ee[wave][g][s * ESTR + j];
        float u0 = 0.f, u1 = 0.f, u2 = 0.f, u3 = 0.f;
        #pragma unroll
        for (int k = 0; k < 24; k += 4) {
            u0 = fmaf(v[k],     Pc[k],     u0);
            u1 = fmaf(v[k + 1], Pc[k + 1], u1);
            u2 = fmaf(v[k + 2], Pc[k + 2], u2);
            u3 = fmaf(v[k + 3], Pc[k + 3], u3);
        }
        u0 = fmaf(v[24], Pc[24], u0);
        u1 = fmaf(v[25], Pc[25], u1);
        vrow[wave][g][j] = ((u0 + u2) + (u1 + u3)) * Ej;   // j>=26 writes 0 (Pc col zero)
        const float* vr = &vrow[wave][g][0];               // broadcast per half
        #pragma unroll
        for (int k = 0; k < 26; ++k) v[k] = vr[k];
    }

    // ---- log partition ----
    float s0 = 0.f, s1 = 0.f, s2 = 0.f, s3 = 0.f;
    #pragma unroll
    for (int k = 0; k < 24; k += 4) {
        s0 += v[k]; s1 += v[k + 1]; s2 += v[k + 2]; s3 += v[k + 3];
    }
    s0 += v[24]; s1 += v[25];
    const float logz = (flog2((s0 + s2) + (s1 + s3)) + 15.f * DELTA) * LN2;

    float local = logz - ne;               // correct at lane 0 (g=0) and lane 32 (g=1)
    const float other = __shfl(local, 32);
    if (lane == 0) red[wave] = local + other;
    __syncthreads();
    if (threadIdx.x == 0) atomicAdd(out, (red[0] + red[1]) + (red[2] + red[3]));
}

extern "C" void kernel_launch(void* const* d_in, const int* in_sizes, int n_in,
                              void* d_out, int out_size, void* d_ws, size_t ws_size,
                              hipStream_t stream) {
    const float* X = (const float*)d_in[0];
    const int*   Y = (const int*)d_in[1];
    const float* W = (const float*)d_in[2];
    const float* T = (const float*)d_in[3];
    float* out = (float*)d_out;
    uint4* wsW = (uint4*)d_ws;                         // 8 KB
    float* wsP = (float*)((char*)d_ws + 8192);         // 4 KB

    hipMemsetAsync(out, 0, sizeof(float), stream);
    prep_kernel<<<1, 64, 0, stream>>>(W, T, wsW, wsP);
    crf_kernel<<<NBLOCKS, 256, 0, stream>>>(X, Y, T, wsW, wsP, out);
}

// Round 5
// 213.340 us; speedup vs baseline: 2.0713x; 1.0114x over previous
//
#include <hip/hip_runtime.h>
#include <math.h>

// CRF negative log-likelihood. Round 5: force-vectorized recurrence DS traffic.
// B=16384, M=16, D=128, L=26. 2 batches per wave (lane = 32g + j).
//
// v_s[j] = 2^{alpha_s[j] + e2[s][j] - s*delta};  v_0 = E_0;
// v_s = (v_{s-1} . P') * E_s,  P'[k][j] = 2^{T2[k][j] - delta} (constant),
// E_s[j] = 2^{e2[s][j]} (MFMA emissions, exponentiated once).
// Per step: 7x ds_read_b128 (v reload) + 1 ds_write_b32; Ej preloaded.

#define B_TOT 16384
#define M_LEN 16
#define D_DIM 128
#define L_LAB 26
#define WPB 4
#define NBLOCKS (B_TOT / (WPB * 2))   // 2048 blocks, 2 batches per wave
#define LOG2E 1.4426950408889634f
#define LN2   0.6931471805599453f
#define DELTA 5.7f
#define ESTR 36                        // Ee row stride in floats (144 B, 16B-aligned)

typedef short v8s __attribute__((ext_vector_type(8)));   // 8 bf16
typedef float v4f __attribute__((ext_vector_type(4)));   // 4 fp32 acc

static __device__ __forceinline__ unsigned bf16u(float f) {
    unsigned u = __float_as_uint(f);
    u += 0x7fff + ((u >> 16) & 1);     // RNE
    return u >> 16;
}
static __device__ __forceinline__ unsigned pkbf(float lo, float hi) {
    return bf16u(lo) | (bf16u(hi) << 16);
}
static __device__ __forceinline__ float fexp2(float x) {
#if __has_builtin(__builtin_amdgcn_exp2f)
    return __builtin_amdgcn_exp2f(x);
#else
    return exp2f(x);
#endif
}
static __device__ __forceinline__ float flog2(float x) {
#if __has_builtin(__builtin_amdgcn_logf)
    return __builtin_amdgcn_logf(x);
#else
    return log2f(x);
#endif
}

// Precompute (a) W MFMA B-fragments, bf16, scaled by log2e, labels zero-padded
// to 32; (b) P' transposed: wsP[j*32+k] = 2^{T[k][j]*log2e - delta}, zero pad.
__global__ void prep_kernel(const float* __restrict__ W, const float* __restrict__ T,
                            uint4* __restrict__ wsW, float* __restrict__ wsP) {
    const int l = threadIdx.x;       // 64 threads
    const int c16 = l & 15, quad = l >> 4;
    #pragma unroll
    for (int f = 0; f < 8; ++f) {
        const int tile = f >> 2, kk = f & 3;
        const int label = tile * 16 + c16;
        const int base = kk * 32 + quad * 8;
        unsigned d[4];
        #pragma unroll
        for (int p = 0; p < 4; ++p) {
            float a = 0.f, bb = 0.f;
            if (label < L_LAB) {
                a  = W[label * D_DIM + base + 2 * p]     * LOG2E;
                bb = W[label * D_DIM + base + 2 * p + 1] * LOG2E;
            }
            d[p] = pkbf(a, bb);
        }
        wsW[l * 8 + f] = make_uint4(d[0], d[1], d[2], d[3]);
    }
    for (int i = l; i < 1024; i += 64) {
        const int j = i >> 5, k = i & 31;
        wsP[i] = (j < L_LAB && k < L_LAB)
               ? exp2f(T[k * L_LAB + j] * LOG2E - DELTA) : 0.f;
    }
}

__global__ __launch_bounds__(256, 4) void crf_kernel(
    const float* __restrict__ X, const int* __restrict__ Y,
    const float* __restrict__ T, const uint4* __restrict__ wsW,
    const float* __restrict__ wsP, float* __restrict__ out)
{
    const int lane = threadIdx.x & 63;
    const int wave = threadIdx.x >> 6;
    const int g = lane >> 5;             // batch half
    const int j = lane & 31;             // label (valid < 26; 26..31 = zero pad)
    const int c16 = lane & 15;           // MFMA col / row-group
    const int quad = lane >> 4;

    __shared__ float Ts[L_LAB * L_LAB];                // natural units (edge)
    __shared__ float Ee[WPB][2][M_LEN * ESTR];         // E = 2^{e2}
    __shared__ float vrow[WPB][2][32];                 // 32 floats: 16B-aligned rows
    __shared__ float red[WPB];

    for (int i = threadIdx.x; i < L_LAB * L_LAB; i += 256) Ts[i] = T[i];

    // W fragments (bf16, pre-scaled)
    uint4 wf[8];
    #pragma unroll
    for (int f = 0; f < 8; ++f) wf[f] = wsW[lane * 8 + f];

    __syncthreads();   // Ts ready

    const int wgid = blockIdx.x * WPB + wave;

    // ---- emissions via MFMA, 2 batches, epilogue applies exp2 ----
    #pragma unroll
    for (int g2 = 0; g2 < 2; ++g2) {
        const float* xb = X + (size_t)(wgid * 2 + g2) * (M_LEN * D_DIM);
        v4f acc0 = {0.f, 0.f, 0.f, 0.f};
        v4f acc1 = {0.f, 0.f, 0.f, 0.f};
        #pragma unroll
        for (int kk = 0; kk < 4; ++kk) {
            const float4* xp = (const float4*)(xb + c16 * D_DIM + kk * 32 + quad * 8);
            float4 xa = xp[0];
            float4 xc = xp[1];
            uint4 au = make_uint4(pkbf(xa.x, xa.y), pkbf(xa.z, xa.w),
                                  pkbf(xc.x, xc.y), pkbf(xc.z, xc.w));
            v8s af = *(v8s*)&au;
            v8s b0 = *(v8s*)&wf[kk];
            v8s b1 = *(v8s*)&wf[4 + kk];
            acc0 = __builtin_amdgcn_mfma_f32_16x16x32_bf16(af, b0, acc0, 0, 0, 0);
            acc1 = __builtin_amdgcn_mfma_f32_16x16x32_bf16(af, b1, acc1, 0, 0, 0);
        }
        // C layout: col = lane&15 (label), row s = quad*4 + r (position)
        #pragma unroll
        for (int r = 0; r < 4; ++r) {
            const int s = quad * 4 + r;
            Ee[wave][g2][s * ESTR + c16]      = fexp2(acc0[r]);
            Ee[wave][g2][s * ESTR + 16 + c16] = fexp2(acc1[r]);  // labels>=26: e2=0 -> E=1
        }
    }
    // Ee written & read by the same wave only: DS pipe in-order, no barrier.

    // ---- P' columns (after MFMA phase to bound VGPR pressure) ----
    float4 Pc4[7];
    {
        const float4* pp = (const float4*)(wsP + j * 32);
        #pragma unroll
        for (int t = 0; t < 7; ++t) Pc4[t] = pp[t];
    }
    // ---- preload per-step E_s[j] (out of the serial RAW chain) ----
    float Ejs[15];
    #pragma unroll
    for (int s = 1; s < M_LEN; ++s) Ejs[s - 1] = Ee[wave][g][s * ESTR + j];

    // ---- node + edge potentials (e2 recovered via log2(E)) ----
    float ne = 0.f;
    if (j < M_LEN) {                       // lanes 0-15 (g=0) and 32-47 (g=1)
        const int bb = wgid * 2 + g;
        const int ys = Y[bb * M_LEN + j];
        ne = flog2(Ee[wave][g][j * ESTR + ys]) * LN2;
        if (j < M_LEN - 1) {
            const int yn = Y[bb * M_LEN + j + 1];
            ne += Ts[ys * L_LAB + yn];
        }
    }
    ne += __shfl_xor(ne, 8);
    ne += __shfl_xor(ne, 4);
    ne += __shfl_xor(ne, 2);
    ne += __shfl_xor(ne, 1);               // valid where (lane&31)==0

    // ---- recurrence: 15 x (fp32 matvec + elementwise E) ----
    float4 v4[7];
    {
        const float4* e0 = (const float4*)&Ee[wave][g][0];   // v_0 = E_0 (28 floats)
        #pragma unroll
        for (int t = 0; t < 7; ++t) v4[t] = e0[t];
    }
    #pragma unroll
    for (int s = 1; s < M_LEN; ++s) {
        float4 u4 = make_float4(0.f, 0.f, 0.f, 0.f);
        #pragma unroll
        for (int t = 0; t < 7; ++t) {
            u4.x = fmaf(v4[t].x, Pc4[t].x, u4.x);
            u4.y = fmaf(v4[t].y, Pc4[t].y, u4.y);
            u4.z = fmaf(v4[t].z, Pc4[t].z, u4.z);
            u4.w = fmaf(v4[t].w, Pc4[t].w, u4.w);
        }
        const float u = (u4.x + u4.z) + (u4.y + u4.w);
        vrow[wave][g][j] = u * Ejs[s - 1];     // j>=26: Pc cols zero -> writes 0
        const float4* vr = (const float4*)&vrow[wave][g][0];
        #pragma unroll
        for (int t = 0; t < 7; ++t) v4[t] = vr[t];   // 7x ds_read_b128
    }

    // ---- log partition (pad entries are 0 after step 15) ----
    float4 sv = make_float4(0.f, 0.f, 0.f, 0.f);
    #pragma unroll
    for (int t = 0; t < 7; ++t) {
        sv.x += v4[t].x; sv.y += v4[t].y; sv.z += v4[t].z; sv.w += v4[t].w;
    }
    const float logz = (flog2((sv.x + sv.z) + (sv.y + sv.w)) + 15.f * DELTA) * LN2;

    float local = logz - ne;               // valid at lane 0 (g=0), lane 32 (g=1)
    const float other = __shfl(local, 32);
    if (lane == 0) red[wave] = local + other;
    __syncthreads();
    if (threadIdx.x == 0) atomicAdd(out, (red[0] + red[1]) + (red[2] + red[3]));
}

extern "C" void kernel_launch(void* const* d_in, const int* in_sizes, int n_in,
                              void* d_out, int out_size, void* d_ws, size_t ws_size,
                              hipStream_t stream) {
    const float* X = (const float*)d_in[0];
    const int*   Y = (const int*)d_in[1];
    const float* W = (const float*)d_in[2];
    const float* T = (const float*)d_in[3];
    float* out = (float*)d_out;
    uint4* wsW = (uint4*)d_ws;                         // 8 KB
    float* wsP = (float*)((char*)d_ws + 8192);         // 4 KB

    hipMemsetAsync(out, 0, sizeof(float), stream);
    prep_kernel<<<1, 64, 0, stream>>>(W, T, wsW, wsP);
    crf_kernel<<<NBLOCKS, 256, 0, stream>>>(X, Y, T, wsW, wsP, out);
}